// Round 4
// baseline (561.152 us; speedup 1.0000x reference)
//
#include <hip/hip_runtime.h>
#include <hip/hip_bf16.h>
#include <math.h>

#define N_NODES 50000
#define N_EDGES 800000
// dims: IN=16, OUT=16, EF=16, H=4, HD=32, DGAT=128

__device__ inline float bf2f(unsigned short u) {
    unsigned t = (unsigned)u << 16;
    return __builtin_bit_cast(float, t);
}
__device__ inline unsigned short f2bf(float f) {
    __hip_bfloat16 h = __float2bfloat16(f);
    return __builtin_bit_cast(unsigned short, h);
}

// ---------------- CSR build ----------------
__global__ void count_kernel(const int* __restrict__ dst, int* __restrict__ counts) {
    int e = blockIdx.x * 256 + threadIdx.x;
    if (e < N_EDGES) atomicAdd(&counts[dst[e]], 1);
}

__global__ void scan_kernel(const int* __restrict__ counts, int* __restrict__ offsets) {
    __shared__ int sdata[1024];
    int tid = threadIdx.x;
    const int chunk = (N_NODES + 1023) / 1024;
    int beg = tid * chunk;
    int end = min(beg + chunk, N_NODES);
    int s = 0;
    for (int j = beg; j < end; ++j) s += counts[j];
    sdata[tid] = s;
    __syncthreads();
    for (int d = 1; d < 1024; d <<= 1) {
        int v = (tid >= d) ? sdata[tid - d] : 0;
        __syncthreads();
        sdata[tid] += v;
        __syncthreads();
    }
    int base = (tid == 0) ? 0 : sdata[tid - 1];
    for (int j = beg; j < end; ++j) { offsets[j] = base; base += counts[j]; }
    if (tid == 0) offsets[N_NODES] = sdata[1023];
}

__global__ void scatter_kernel(const int* __restrict__ src, const int* __restrict__ dst,
                               const int* __restrict__ offsets,
                               int* __restrict__ cursor, int* __restrict__ csr_eid,
                               int* __restrict__ csr_src) {
    int e = blockIdx.x * 256 + threadIdx.x;
    if (e < N_EDGES) {
        int d = dst[e];
        int pos = offsets[d] + atomicAdd(&cursor[d], 1);
        csr_eid[pos] = e;
        csr_src[pos] = src[e];
    }
}

// ---------------- Node-level precompute: y[n][f*16+o] = sum_i x[n,i] Wnn[f*256+i*16+o] ----------------
// Also t[n][o] = sum_i x[n,i] * bnn[i*16+o]  (exact b_nn handling).
// 4 nodes per 256-block; lane owns k = 4*lane..4*lane+3 (f=lane>>2, o=(lane&3)*4+j).
__global__ __launch_bounds__(256) void y_kernel(const float* __restrict__ x,
                                                const float* __restrict__ Wnn,
                                                const float* __restrict__ bnn,
                                                unsigned short* __restrict__ y_bf,
                                                float* __restrict__ t_arr) {
    int tid = threadIdx.x;
    int n = blockIdx.x * 4 + (tid >> 6);
    int lane = tid & 63;
    if (n >= N_NODES) return;
    int f = lane >> 2;
    int ob = (lane & 3) * 4;
    const float* Wbase = Wnn + f * 256 + ob;
    const float* xr = x + (size_t)n * 16;
    float a0 = 0.f, a1 = 0.f, a2 = 0.f, a3 = 0.f;
#pragma unroll
    for (int i = 0; i < 16; ++i) {
        float4 w4 = *(const float4*)(Wbase + i * 16);
        float xi = xr[i];
        a0 = fmaf(xi, w4.x, a0);
        a1 = fmaf(xi, w4.y, a1);
        a2 = fmaf(xi, w4.z, a2);
        a3 = fmaf(xi, w4.w, a3);
    }
    ushort4 o4;
    o4.x = f2bf(a0); o4.y = f2bf(a1); o4.z = f2bf(a2); o4.w = f2bf(a3);
    *(ushort4*)(y_bf + (size_t)n * 256 + lane * 4) = o4;
    if (lane < 16) {
        float tv = 0.f;
#pragma unroll
        for (int i = 0; i < 16; ++i) tv = fmaf(xr[i], bnn[i * 16 + lane], tv);
        t_arr[(size_t)n * 16 + lane] = tv;
    }
}

// ---------------- NNConv aggregate (factorized) + root + relu + GAT projection ----------------
// One wave per node-chunk. Per edge: agg[o] += sum_f ea[eid][f]*y[s][f*16+o] + t[s][o].
// Lane l: f=l>>2 (const), 4 accumulators for o=(l&3)*4+j via one ushort4 y load.
#define NN_BLOCKS 1024
#define NN_WAVES (NN_BLOCKS * 4)
__global__ __launch_bounds__(256) void nnagg_kernel(
    const float* __restrict__ x, const unsigned short* __restrict__ y_bf,
    const float* __restrict__ t_arr, const float* __restrict__ ea,
    const int* __restrict__ csr_eid, const int* __restrict__ csr_src,
    const int* __restrict__ offsets,
    const float* __restrict__ Wroot, const float* __restrict__ becc,
    const float* __restrict__ Wgat, const float* __restrict__ asrc,
    const float* __restrict__ adst,
    unsigned short* __restrict__ z_bf, float* __restrict__ es, float* __restrict__ ed)
{
    __shared__ float hx[4][16];
    const int wid = threadIdx.x >> 6;
    const int lane = threadIdx.x & 63;
    const int f = lane >> 2;
    const int ob = (lane & 3) * 4;

    float wg0[16], wg1[16];
#pragma unroll
    for (int i = 0; i < 16; ++i) {
        wg0[i] = Wgat[i * 128 + lane];
        wg1[i] = Wgat[i * 128 + 64 + lane];
    }
    const float as0 = asrc[lane], as1 = asrc[lane + 64];
    const float ad0 = adst[lane], ad1 = adst[lane + 64];

    const int wgid = blockIdx.x * 4 + wid;
    const int per = (N_NODES + NN_WAVES - 1) / NN_WAVES;
    const int n0 = wgid * per;
    const int n1 = min(n0 + per, N_NODES);

    for (int n = n0; n < n1; ++n) {
        const int beg = offsets[n], end = offsets[n + 1];
        float a0 = 0.f, a1 = 0.f, a2 = 0.f, a3 = 0.f;
        for (int j = beg; j < end; ++j) {
            int eid = csr_eid[j];
            int s = csr_src[j];
            float ef = ea[(size_t)eid * 16 + f];
            ushort4 y4 = *(const ushort4*)(y_bf + (size_t)s * 256 + lane * 4);
            float4 t4 = *(const float4*)(t_arr + (size_t)s * 16 + ob);
            a0 = fmaf(ef, bf2f(y4.x), a0) + t4.x * 0.0625f;  // t added by 16 lanes (f groups) -> /16
            a1 = fmaf(ef, bf2f(y4.y), a1) + t4.y * 0.0625f;
            a2 = fmaf(ef, bf2f(y4.z), a2) + t4.z * 0.0625f;
            a3 = fmaf(ef, bf2f(y4.w), a3) + t4.w * 0.0625f;
        }
        // reduce over f: lanes {(l&3)+4f} hold same o-quad
#pragma unroll
        for (int k = 4; k <= 32; k <<= 1) {
            a0 += __shfl_xor(a0, k, 64);
            a1 += __shfl_xor(a1, k, 64);
            a2 += __shfl_xor(a2, k, 64);
            a3 += __shfl_xor(a3, k, 64);
        }
        // root weight + bias + relu (per lane: its 4 o's; redundant across f-groups)
        const float* xr = x + (size_t)n * 16;
        float r0 = becc[ob + 0], r1 = becc[ob + 1], r2 = becc[ob + 2], r3 = becc[ob + 3];
#pragma unroll
        for (int i = 0; i < 16; ++i) {
            float4 wr = *(const float4*)(Wroot + i * 16 + ob);
            float xi = xr[i];
            r0 = fmaf(xi, wr.x, r0);
            r1 = fmaf(xi, wr.y, r1);
            r2 = fmaf(xi, wr.z, r2);
            r3 = fmaf(xi, wr.w, r3);
        }
        float h0 = fmaxf(a0 + r0, 0.f), h1 = fmaxf(a1 + r1, 0.f);
        float h2 = fmaxf(a2 + r2, 0.f), h3 = fmaxf(a3 + r3, 0.f);
        if (lane < 4) {
            hx[wid][lane * 4 + 0] = h0;
            hx[wid][lane * 4 + 1] = h1;
            hx[wid][lane * 4 + 2] = h2;
            hx[wid][lane * 4 + 3] = h3;
        }
        asm volatile("s_waitcnt lgkmcnt(0)" ::: "memory");
        // z = h @ Wgat (dims lane, lane+64)
        float z0 = 0.f, z1 = 0.f;
#pragma unroll
        for (int i = 0; i < 16; ++i) {
            float hv = hx[wid][i];
            z0 = fmaf(hv, wg0[i], z0);
            z1 = fmaf(hv, wg1[i], z1);
        }
        z_bf[(size_t)n * 128 + lane] = f2bf(z0);
        z_bf[(size_t)n * 128 + 64 + lane] = f2bf(z1);
        // es/ed from f32 z
        float p0s = z0 * as0, p1s = z1 * as1;
        float p0d = z0 * ad0, p1d = z1 * ad1;
#pragma unroll
        for (int k = 1; k <= 16; k <<= 1) {
            p0s += __shfl_xor(p0s, k, 64);
            p1s += __shfl_xor(p1s, k, 64);
            p0d += __shfl_xor(p0d, k, 64);
            p1d += __shfl_xor(p1d, k, 64);
        }
        if ((lane & 31) == 0) {
            int hh = lane >> 5;
            es[(size_t)n * 4 + hh]     = p0s;
            es[(size_t)n * 4 + hh + 2] = p1s;
            ed[(size_t)n * 4 + hh]     = p0d;
            ed[(size_t)n * 4 + hh + 2] = p1d;
        }
    }
}

// ---------------- GAT aggregation + bias + relu + final fc ----------------
// one wave per node; z in bf16 (half the gather bytes), 2-edge unroll for MLP.
__global__ void gat_kernel(const unsigned short* __restrict__ z_bf, const float* __restrict__ es,
                           const float* __restrict__ ed, const int* __restrict__ csr_src,
                           const int* __restrict__ offsets,
                           const float* __restrict__ bgat, const float* __restrict__ Wfc,
                           const float* __restrict__ bfc, float* __restrict__ out) {
    int wid = threadIdx.x >> 6;
    int lane = threadIdx.x & 63;
    int n = blockIdx.x * 4 + wid;
    if (n >= N_NODES) return;
    int head = lane >> 4;
    float edh = ed[(size_t)n * 4 + head];
    int beg = offsets[n], end = offsets[n + 1];
    int deg = end - beg;
    float den = 0.f, a0 = 0.f, a1 = 0.f;
    int s_l = (lane < deg) ? csr_src[beg + lane] : 0;
    int m64 = min(deg, 64);
    int el = 0;
    for (; el + 2 <= m64; el += 2) {
        int sA = __shfl(s_l, el, 64);
        int sB = __shfl(s_l, el + 1, 64);
        float lA = es[(size_t)sA * 4 + head] + edh;
        float lB = es[(size_t)sB * 4 + head] + edh;
        lA = (lA > 0.f) ? lA : 0.2f * lA;
        lB = (lB > 0.f) ? lB : 0.2f * lB;
        float wA = __expf(lA), wB = __expf(lB);
        ushort2 zA = *(const ushort2*)(z_bf + (size_t)sA * 128 + 2 * lane);
        ushort2 zB = *(const ushort2*)(z_bf + (size_t)sB * 128 + 2 * lane);
        den += wA + wB;
        a0 = fmaf(wA, bf2f(zA.x), a0);
        a1 = fmaf(wA, bf2f(zA.y), a1);
        a0 = fmaf(wB, bf2f(zB.x), a0);
        a1 = fmaf(wB, bf2f(zB.y), a1);
    }
    for (; el < m64; ++el) {
        int s = __shfl(s_l, el, 64);
        float l = es[(size_t)s * 4 + head] + edh;
        l = (l > 0.f) ? l : 0.2f * l;
        float w = __expf(l);
        den += w;
        ushort2 zv = *(const ushort2*)(z_bf + (size_t)s * 128 + 2 * lane);
        a0 = fmaf(w, bf2f(zv.x), a0);
        a1 = fmaf(w, bf2f(zv.y), a1);
    }
    for (int j = beg + 64; j < end; ++j) {
        int s = csr_src[j];
        float l = es[(size_t)s * 4 + head] + edh;
        l = (l > 0.f) ? l : 0.2f * l;
        float w = __expf(l);
        den += w;
        ushort2 zv = *(const ushort2*)(z_bf + (size_t)s * 128 + 2 * lane);
        a0 = fmaf(w, bf2f(zv.x), a0);
        a1 = fmaf(w, bf2f(zv.y), a1);
    }
    float inv = 1.f / (den + 1e-16f);
    float2 bg = *(const float2*)(bgat + 2 * lane);
    float g0 = fmaxf(fmaf(a0, inv, bg.x), 0.f);
    float g1 = fmaxf(fmaf(a1, inv, bg.y), 0.f);
    float2 wf = *(const float2*)(Wfc + 2 * lane);
    float p = g0 * wf.x + g1 * wf.y;
    for (int k = 32; k > 0; k >>= 1) p += __shfl_down(p, k, 64);
    if (lane == 0) out[n] = p + bfc[0];
}

extern "C" void kernel_launch(void* const* d_in, const int* in_sizes, int n_in,
                              void* d_out, int out_size, void* d_ws, size_t ws_size,
                              hipStream_t stream) {
    const float* x     = (const float*)d_in[0];
    const int*   eidx  = (const int*)d_in[1];
    const float* ea    = (const float*)d_in[2];
    const float* Wnn   = (const float*)d_in[3];
    const float* bnn   = (const float*)d_in[4];
    const float* Wroot = (const float*)d_in[5];
    const float* becc  = (const float*)d_in[6];
    const float* Wgat  = (const float*)d_in[7];
    const float* asrc  = (const float*)d_in[8];
    const float* adst  = (const float*)d_in[9];
    const float* bgat  = (const float*)d_in[10];
    const float* Wfc   = (const float*)d_in[11];
    const float* bfc   = (const float*)d_in[12];
    const int* src = eidx;
    const int* dst = eidx + N_EDGES;
    float* out = (float*)d_out;

    char* ws = (char*)d_ws;
    size_t off = 0;
    auto alloc = [&](size_t bytes) {
        void* p = ws + off;
        off += (bytes + 255) & ~(size_t)255;
        return p;
    };
    int*   counts  = (int*)alloc((size_t)N_NODES * 4);
    int*   cursor  = (int*)alloc((size_t)N_NODES * 4);
    int*   offsets = (int*)alloc((size_t)(N_NODES + 1) * 4);
    int*   csr_eid = (int*)alloc((size_t)N_EDGES * 4);
    int*   csr_src = (int*)alloc((size_t)N_EDGES * 4);
    unsigned short* y_bf = (unsigned short*)alloc((size_t)N_NODES * 256 * 2);
    float* t_arr   = (float*)alloc((size_t)N_NODES * 16 * 4);
    unsigned short* z_bf = (unsigned short*)alloc((size_t)N_NODES * 128 * 2);
    float* es      = (float*)alloc((size_t)N_NODES * 4 * 4);
    float* ed      = (float*)alloc((size_t)N_NODES * 4 * 4);

    hipMemsetAsync(counts, 0, (size_t)N_NODES * 4, stream);
    hipMemsetAsync(cursor, 0, (size_t)N_NODES * 4, stream);

    int eb = (N_EDGES + 255) / 256;
    count_kernel<<<eb, 256, 0, stream>>>(dst, counts);
    scan_kernel<<<1, 1024, 0, stream>>>(counts, offsets);
    scatter_kernel<<<eb, 256, 0, stream>>>(src, dst, offsets, cursor, csr_eid, csr_src);
    y_kernel<<<(N_NODES + 3) / 4, 256, 0, stream>>>(x, Wnn, bnn, y_bf, t_arr);
    nnagg_kernel<<<NN_BLOCKS, 256, 0, stream>>>(x, y_bf, t_arr, ea, csr_eid, csr_src, offsets,
                                                Wroot, becc, Wgat, asrc, adst, z_bf, es, ed);
    gat_kernel<<<(N_NODES + 3) / 4, 256, 0, stream>>>(z_bf, es, ed, csr_src, offsets, bgat, Wfc, bfc, out);
}